// Round 3
// baseline (1609.526 us; speedup 1.0000x reference)
//
#include <hip/hip_runtime.h>
#include <cstdint>

// Block_32401233281211: SAM-style windowed-attention transformer block.
// I/O dtype: FLOAT32. Internal GEMMs + attention: bf16 MFMA.
// B=8, H=W=64, C=768, heads=12, hd=64, FF=3072, WS=14 -> pad to 70x70,
// 200 windows x 196 tokens = 39200 window-token rows.
// R8: attention half-blocks (passed, ~200us). GEMM was m97 2-barrier 128x128
//     at ~470 TF, 73% of runtime.
// R9 (this round): GEMM -> 256x256 BK=64 512-thread pipelined kernel:
//   - double-buffered LDS (128 KiB), global_load_lds width=16
//   - counted vmcnt(8) on RAW barriers: next tile's 8 loads stay in flight
//     across the barrier (T3/T4); 64 MFMA per drain (vs 16 before)
//   - T2 XOR swizzle chunk^=(row&7) via inverse-swizzled GLOBAL source +
//     swizzled ds_read (rule 21: both-sides, linear gload_lds dest)
//   - T5 setprio around MFMA clusters
//   - sched_barrier(0) fences around all raw barriers / waitcnts

typedef unsigned short u16;
typedef __attribute__((ext_vector_type(8))) short short8;   // 8 x bf16
typedef __attribute__((ext_vector_type(4))) float f32x4;

__device__ __forceinline__ u16 f2b(float f) {
    union { float f; unsigned int i; } x; x.f = f;
    unsigned int u = x.i;
    return (u16)((u + 0x7fffu + ((u >> 16) & 1u)) >> 16);   // RNE
}
__device__ __forceinline__ float b2f(u16 u) {
    union { unsigned int i; float f; } x; x.i = ((unsigned int)u) << 16; return x.f;
}

// async global->LDS, 16 B per lane. LDS dest = wave-uniform base + lane*16.
__device__ __forceinline__ void gload16(const u16* g, u16* l) {
    __builtin_amdgcn_global_load_lds(
        (const __attribute__((address_space(1))) unsigned int*)g,
        (__attribute__((address_space(3))) unsigned int*)l, 16, 0, 0);
}

// bijective XCD swizzle (m204)
__device__ __forceinline__ int xcd_swz(int bid, int nwg) {
    int q = nwg >> 3, r = nwg & 7;
    int x = bid & 7, lo = bid >> 3;
    return (x < r ? x * (q + 1) : r * (q + 1) + (x - r) * q) + lo;
}

// ---------------------------------------------------------------- transpose
__global__ __launch_bounds__(256) void transpose_k(
    const float* __restrict__ in, u16* __restrict__ out, int R, int C)
{
    __shared__ float tile[32][33];
    int bpc = C >> 5;
    int r0 = (blockIdx.x / bpc) << 5;
    int c0 = (blockIdx.x % bpc) << 5;
    int lx = threadIdx.x & 31, ly = threadIdx.x >> 5;
#pragma unroll
    for (int s = 0; s < 32; s += 8)
        tile[ly + s][lx] = in[(size_t)(r0 + ly + s) * C + c0 + lx];
    __syncthreads();
#pragma unroll
    for (int s = 0; s < 32; s += 8)
        out[(size_t)(c0 + ly + s) * R + r0 + lx] = f2b(tile[lx][ly + s]);
}

// ---------------------------------------------------------------- layernorm
__global__ __launch_bounds__(256) void ln_kernel(
    const float* __restrict__ in, const float* __restrict__ g,
    const float* __restrict__ beta, u16* __restrict__ out, int windowed,
    int row_base)
{
    __shared__ float sbuf[4];
    int tid = threadIdx.x;
    size_t orow = (size_t)blockIdx.x * 768;
    size_t irow;
    if (windowed) {
        int r = row_base + blockIdx.x;
        int win = r / 196, t = r % 196;
        int p = t / 14, q = t % 14;
        int b = win / 25, wt = win % 25;
        int i = (wt / 5) * 14 + p, j = (wt % 5) * 14 + q;
        if (i >= 64 || j >= 64) {
            out[orow + tid] = 0; out[orow + tid + 256] = 0; out[orow + tid + 512] = 0;
            return;
        }
        irow = (((size_t)b * 64 + i) * 64 + j) * 768;
    } else {
        irow = (size_t)blockIdx.x * 768;
    }
    float v0 = in[irow + tid];
    float v1 = in[irow + tid + 256];
    float v2 = in[irow + tid + 512];
    float s = v0 + v1 + v2;
#pragma unroll
    for (int off = 32; off; off >>= 1) s += __shfl_xor(s, off, 64);
    if ((tid & 63) == 0) sbuf[tid >> 6] = s;
    __syncthreads();
    float mean = (sbuf[0] + sbuf[1] + sbuf[2] + sbuf[3]) * (1.f / 768.f);
    __syncthreads();
    float d0 = v0 - mean, d1 = v1 - mean, d2 = v2 - mean;
    float sq = d0 * d0 + d1 * d1 + d2 * d2;
#pragma unroll
    for (int off = 32; off; off >>= 1) sq += __shfl_xor(sq, off, 64);
    if ((tid & 63) == 0) sbuf[tid >> 6] = sq;
    __syncthreads();
    float var = (sbuf[0] + sbuf[1] + sbuf[2] + sbuf[3]) * (1.f / 768.f);
    float rs = rsqrtf(var + 1e-6f);
    out[orow + tid]       = f2b(d0 * rs * g[tid]       + beta[tid]);
    out[orow + tid + 256] = f2b(d1 * rs * g[tid + 256] + beta[tid + 256]);
    out[orow + tid + 512] = f2b(d2 * rs * g[tid + 512] + beta[tid + 512]);
}

// ---------------------------------------------------------------- GEMM 256x256
// C(MxN) = A(MxK) @ Bt(NxK)^T + bias. 512 threads = 8 waves (2M x 4N), each
// wave owns a 128x64 output tile: acc[8][4] 16x16 fragments.
// K-loop: one BK=64 tile per group; double-buffered LDS; per group:
//   B1(raw) | issue 8 gload_lds for tile t+1 | vmcnt(8) | B2(raw) | 4 phases
// Phases: (mh,nh) = (0,0),(0,1),(1,1),(1,0); A reloaded at mh flip, B per nh.
// Swizzle: LDS row = 64 elems (128 B); k-chunk' = chunk ^ (row&7). Staged via
// inverse-swizzled global source (involution), read with same XOR.
// Tail M-rows stage garbage (reads land in adjacent workspace); row-local in
// MFMA; epilogue skips rows >= M.
#define GBM 256
#define GBN 256
#define GBK 64

__device__ __forceinline__ short8 lds_frag(const u16* base, int row, int ks,
                                           int quad, int l7) {
    return *(const short8*)(base + row * 64 + ((((ks << 2) + quad) ^ l7) << 3));
}

template <int EPI>
__global__ __launch_bounds__(512) void gemm256(
    const u16* __restrict__ A, const u16* __restrict__ Bt,
    const float* __restrict__ bias, void* __restrict__ CoutV,
    const float* __restrict__ resid, int M, int N, int K, int row_base)
{
    __shared__ __align__(16) u16 LdsA[2][GBM * GBK];   // 64 KB
    __shared__ __align__(16) u16 LdsB[2][GBN * GBK];   // 64 KB
    const int tid = threadIdx.x;
    const int lane = tid & 63, wave = tid >> 6;        // 8 waves
    const int wr = wave >> 2, wc = wave & 3;           // 2 x 4
    const int quad = lane >> 4, l16 = lane & 15, l7 = lane & 7;
    const int ntile = N / GBN;
    const int swz = xcd_swz(blockIdx.x, gridDim.x);
    const int m0 = (swz / ntile) * GBM;
    const int n0 = (swz % ntile) * GBN;

    // staging lane constants: segment = 8 rows x 128 B; lane i covers
    // row (i>>3), source k-chunk (i&7)^(i>>3) (inverse swizzle).
    const int rl = lane >> 3;
    const int cl = ((lane & 7) ^ rl) << 3;             // k elem offset
    const int sA = wave * 4;                           // this wave's 4 segs (x A,B)
    int aoff[4], boff[4];                              // 32-bit elem offsets
    int lA[4], lB[4];                                  // LDS elem offsets (buf 0)
#pragma unroll
    for (int q = 0; q < 4; q++) {
        aoff[q] = (m0 + (sA + q) * 8 + rl) * K + cl;
        boff[q] = (n0 + (sA + q) * 8 + rl) * K + cl;
        lA[q] = (sA + q) * 512;
        lB[q] = (sA + q) * 512;
    }

    f32x4 acc[8][4] = {};
    const int nt = K / GBK;

    // prologue: stage K-tile 0 into buffer 0
#pragma unroll
    for (int q = 0; q < 4; q++) {
        gload16(A + aoff[q],  &LdsA[0][lA[q]]);
        gload16(Bt + boff[q], &LdsB[0][lB[q]]);
    }

#pragma unroll 1
    for (int g = 0; g < nt; ++g) {
        const int cur = g & 1;
        __builtin_amdgcn_sched_barrier(0);
        __builtin_amdgcn_s_barrier();                  // B1: prev reads done
        __builtin_amdgcn_sched_barrier(0);
        if (g + 1 < nt) {
            const int koff = (g + 1) * GBK;
            const int nboff = (cur ^ 1) * (GBM * GBK);
#pragma unroll
            for (int q = 0; q < 4; q++) {
                gload16(A + aoff[q] + koff,  &LdsA[0][nboff + lA[q]]);
                gload16(Bt + boff[q] + koff, &LdsB[0][nboff + lB[q]]);
            }
            __builtin_amdgcn_sched_barrier(0);
            asm volatile("s_waitcnt vmcnt(8)" ::: "memory");   // tile g done
        } else {
            asm volatile("s_waitcnt vmcnt(0)" ::: "memory");
        }
        __builtin_amdgcn_sched_barrier(0);
        __builtin_amdgcn_s_barrier();                  // B2: tile g valid (all waves)
        __builtin_amdgcn_sched_barrier(0);

        const u16* Ab = &LdsA[cur][0];
        const u16* Bb = &LdsB[cur][0];
        short8 a[4][2], b[2][2];

        // ---- phase 0: quadrant (0,0) — load A-half 0, B-quarter 0
#pragma unroll
        for (int m = 0; m < 4; m++)
#pragma unroll
            for (int ks = 0; ks < 2; ks++)
                a[m][ks] = lds_frag(Ab, wr * 128 + m * 16 + l16, ks, quad, l7);
#pragma unroll
        for (int n = 0; n < 2; n++)
#pragma unroll
            for (int ks = 0; ks < 2; ks++)
                b[n][ks] = lds_frag(Bb, wc * 64 + n * 16 + l16, ks, quad, l7);
        __builtin_amdgcn_s_setprio(1);
#pragma unroll
        for (int m = 0; m < 4; m++)
#pragma unroll
            for (int n = 0; n < 2; n++)
#pragma unroll
                for (int ks = 0; ks < 2; ks++)
                    acc[m][n] = __builtin_amdgcn_mfma_f32_16x16x32_bf16(
                        a[m][ks], b[n][ks], acc[m][n], 0, 0, 0);
        __builtin_amdgcn_s_setprio(0);

        // ---- phase 1: quadrant (0,1) — load B-quarter 1
#pragma unroll
        for (int n = 0; n < 2; n++)
#pragma unroll
            for (int ks = 0; ks < 2; ks++)
                b[n][ks] = lds_frag(Bb, wc * 64 + 32 + n * 16 + l16, ks, quad, l7);
        __builtin_amdgcn_s_setprio(1);
#pragma unroll
        for (int m = 0; m < 4; m++)
#pragma unroll
            for (int n = 0; n < 2; n++)
#pragma unroll
                for (int ks = 0; ks < 2; ks++)
                    acc[m][2 + n] = __builtin_amdgcn_mfma_f32_16x16x32_bf16(
                        a[m][ks], b[n][ks], acc[m][2 + n], 0, 0, 0);
        __builtin_amdgcn_s_setprio(0);

        // ---- phase 2: quadrant (1,1) — reload A (half 1), reuse B-quarter 1
#pragma unroll
        for (int m = 0; m < 4; m++)
#pragma unroll
            for (int ks = 0; ks < 2; ks++)
                a[m][ks] = lds_frag(Ab, wr * 128 + 64 + m * 16 + l16, ks, quad, l7);
        __builtin_amdgcn_s_setprio(1);
#pragma unroll
        for (int m = 0; m < 4; m++)
#pragma unroll
            for (int n = 0; n < 2; n++)
#pragma unroll
                for (int ks = 0; ks < 2; ks++)
                    acc[4 + m][2 + n] = __builtin_amdgcn_mfma_f32_16x16x32_bf16(
                        a[m][ks], b[n][ks], acc[4 + m][2 + n], 0, 0, 0);
        __builtin_amdgcn_s_setprio(0);

        // ---- phase 3: quadrant (1,0) — reload B-quarter 0, reuse A-half 1
#pragma unroll
        for (int n = 0; n < 2; n++)
#pragma unroll
            for (int ks = 0; ks < 2; ks++)
                b[n][ks] = lds_frag(Bb, wc * 64 + n * 16 + l16, ks, quad, l7);
        __builtin_amdgcn_s_setprio(1);
#pragma unroll
        for (int m = 0; m < 4; m++)
#pragma unroll
            for (int n = 0; n < 2; n++)
#pragma unroll
                for (int ks = 0; ks < 2; ks++)
                    acc[4 + m][n] = __builtin_amdgcn_mfma_f32_16x16x32_bf16(
                        a[m][ks], b[n][ks], acc[4 + m][n], 0, 0, 0);
        __builtin_amdgcn_s_setprio(0);
    }

    // ---- epilogue
#pragma unroll
    for (int mi = 0; mi < 8; mi++) {
#pragma unroll
        for (int ni = 0; ni < 4; ni++) {
            const int gn = n0 + wc * 64 + ni * 16 + l16;
            const float bv = bias[gn];
#pragma unroll
            for (int r = 0; r < 4; r++) {
                const int row = m0 + wr * 128 + mi * 16 + quad * 4 + r;
                if (row >= M) continue;
                float v = acc[mi][ni][r] + bv;
                if (EPI == 0) {
                    ((u16*)CoutV)[(size_t)row * N + gn] = f2b(v);
                } else if (EPI == 1) {
                    int grow = row_base + row;
                    int win = grow / 196, t = grow % 196;
                    int p = t / 14, q = t % 14;
                    int b_ = win / 25, wt = win % 25;
                    int i = (wt / 5) * 14 + p, j = (wt % 5) * 14 + q;
                    if (i < 64 && j < 64) {
                        size_t idx = (((size_t)b_ * 64 + i) * 64 + j) * 768 + gn;
                        ((float*)CoutV)[idx] = resid[idx] + v;
                    }
                } else if (EPI == 2) {
                    float gl = 0.5f * v * (1.0f + erff(v * 0.70710678118654752f));
                    ((u16*)CoutV)[(size_t)row * N + gn] = f2b(gl);
                } else {
                    size_t idx = (size_t)(row_base + row) * 768 + gn;
                    ((float*)CoutV)[idx] = resid[idx] + v;
                }
            }
        }
    }
}

// ---------------------------------------------------------------- attention v5
// (unchanged from R8 — verified passing)
#define AT_W 72
#define PB_W 40

__global__ __launch_bounds__(256) void attn_mfma(
    const u16* __restrict__ qkv,          // [nw*196][2304] = [..][3][12][64]
    const float* __restrict__ relh, const float* __restrict__ relw, // [27][64]
    u16* __restrict__ out)                // [nw*196][768]
{
    __shared__ __align__(16) u16 pbuf[4][32 * PB_W];     // 10240 B (rel_ext alias)
    __shared__ __align__(16) u16 Kc[64 * AT_W];          //  9216 B
    __shared__ __align__(16) u16 Vt[64 * AT_W];          //  9216 B
    u16* rel_ext = &pbuf[0][0];                          // 128*32*2 = 8192 B

    const int nwg = gridDim.x;
    const int swzb = xcd_swz(blockIdx.x, nwg);
    const int win = swzb / 24, rem = swzb % 24;
    const int head = rem >> 1, half = rem & 1;
    const int row0 = half * 128;
    const int tid = threadIdx.x, lane = tid & 63, wave = tid >> 6;
    const int quad = lane >> 4, l16 = lane & 15;
    const size_t base = (size_t)win * 196 * 2304 + (size_t)head * 64;

    short8 qf[2][2];
#pragma unroll
    for (int mi = 0; mi < 2; mi++) {
        int tok = row0 + wave * 32 + mi * 16 + l16;
        int rt = tok < 196 ? tok : 195;
        const u16* qp = qkv + base + (size_t)rt * 2304 + quad * 8;
        qf[mi][0] = *(const short8*)(qp);
        qf[mi][1] = *(const short8*)(qp + 32);
    }

    for (int e = tid; e < 64 * 64; e += 256) {
        int rr = e >> 6, cc = e & 63;
        float v = 0.f;
        if (rr < 27)      v = 8.f * relh[rr * 64 + cc];
        else if (rr < 54) v = 8.f * relw[(rr - 27) * 64 + cc];
        Kc[rr * AT_W + cc] = f2b(v);
    }
    if (tid < 128) {
        u16* rp = rel_ext + tid * 32;
        uint4 z = make_uint4(0u, 0u, 0u, 0u);
        *(uint4*)(rp) = z; *(uint4*)(rp + 8) = z;
        *(uint4*)(rp + 16) = z; *(uint4*)(rp + 24) = z;
        rp[31] = f2b(-1e30f);
    }
    __syncthreads();

#pragma unroll
    for (int cb = 0; cb < 2; cb++) {
#pragma unroll
        for (int nt = 0; nt < 2; nt++) {
            const u16* kp_ = Kc + (cb * 32 + nt * 16 + l16) * AT_W + quad * 8;
            short8 b0 = *(const short8*)(kp_);
            short8 b1 = *(const short8*)(kp_ + 32);
            int i = cb * 32 + nt * 16 + l16;
#pragma unroll
            for (int mi = 0; mi < 2; mi++) {
                f32x4 c = {};
                c = __builtin_amdgcn_mfma_f32_16x16x32_bf16(qf[mi][0], b0, c, 0, 0, 0);
                c = __builtin_amdgcn_mfma_f32_16x16x32_bf16(qf[mi][1], b1, c, 0, 0, 0);
#pragma unroll
                for (int r = 0; r < 4; r++) {
                    int row = wave * 32 + mi * 16 + quad * 4 + r;
                    int grow = row0 + row;
                    int rowB = grow < 196 ? grow : 195;
                    int p = rowB / 14, qq = rowB % 14;
                    if (i < 27) {
                        int t = p + 13 - i;
                        if (t >= 0 && t < 14) rel_ext[row * 32 + t] = f2b(c[r]);
                    } else if (i < 54) {
                        int t = qq + 13 - (i - 27);
                        if (t >= 0 && t < 14) rel_ext[row * 32 + 14 + t] = f2b(c[r]);
                    }
                }
            }
        }
    }
    short8 qe[2];
#pragma unroll
    for (int mi = 0; mi < 2; mi++)
        qe[mi] = *(const short8*)(rel_ext + (wave * 32 + mi * 16 + l16) * 32 + quad * 8);

    f32x4 acc[2][4] = {};
    float ml_[2][4], ll_[2][4];
#pragma unroll
    for (int mi = 0; mi < 2; mi++)
#pragma unroll
        for (int r = 0; r < 4; r++) { ml_[mi][r] = -1e30f; ll_[mi][r] = 0.f; }

#pragma unroll 1
    for (int c = 0; c < 4; c++) {
        const int kbase = c * 64;
        __syncthreads();
        {
            int key = tid >> 2;
            int cg  = (tid & 3) << 4;
            int gk = kbase + key;
            uint4 k0 = make_uint4(0u,0u,0u,0u), k1 = k0, v0 = k0, v1 = k0;
            if (gk < 196) {
                const u16* kp_ = qkv + base + 768  + (size_t)gk * 2304 + cg;
                const u16* vp_ = qkv + base + 1536 + (size_t)gk * 2304 + cg;
                k0 = *(const uint4*)(kp_); k1 = *(const uint4*)(kp_ + 8);
                v0 = *(const uint4*)(vp_); v1 = *(const uint4*)(vp_ + 8);
            }
            *(uint4*)(Kc + key * AT_W + cg)     = k0;
            *(uint4*)(Kc + key * AT_W + cg + 8) = k1;
            union { uint4 u; u16 h[8]; } a, b; a.u = v0; b.u = v1;
#pragma unroll
            for (int i = 0; i < 8; i++) Vt[(cg + i) * AT_W + key] = a.h[i];
#pragma unroll
            for (int i = 0; i < 8; i++) Vt[(cg + 8 + i) * AT_W + key] = b.h[i];
        }
        __syncthreads();

        short8 bo[4];
        {
            const u16 one = 0x3F80;
#pragma unroll
            for (int nt = 0; nt < 4; nt++) {
                int key = kbase + nt * 16 + l16;
                int inval = key >= 196;
                int kp = key / 14, kq = key - kp * 14;
                union { short8 s; u16 h[8]; } u;
#pragma unroll
                for (int j = 0; j < 8; j++) {
                    int t = quad * 8 + j;
                    u16 v = 0;
                    if (!inval && t == kp) v = one;
                    if (!inval && t >= 14 && (t - 14) == kq) v = one;
                    if (inval && t == 31) v = one;
                    u.h[j] = v;
                }
                bo[nt] = u.s;
            }
        }

        f32x4 s23[2][2];
#pragma unroll
        for (int mi = 0; mi < 2; mi++) {
            f32x4 s[4];
            __builtin_amdgcn_s_setprio(1);
#pragma unroll
            for (int nt = 0; nt < 4; nt++) {
                const u16* kp_ = Kc + (nt * 16 + l16) * AT_W + quad * 8;
                short8 kf0 = *(const short8*)(kp_);
                short8 kf1 = *(const short8*)(kp_ + 32);
                f32x4 t = {};
                t = __builtin_amdgcn_mfma_f32_16x16x32_bf16(qf[mi][0], kf0, t, 0, 0, 0);
                t = __builtin_amdgcn_mfma_f32_16x16x32_bf16(qf[mi][1], kf1, t, 0, 0, 0);
                t = __builtin_amdgcn_mfma_f32_16x16x32_bf16(qe[mi],    bo[nt], t, 0, 0, 0);
                s[nt] = t * 0.125f;
            }
            __builtin_amdgcn_s_setprio(0);
#pragma unroll
            for (int r = 0; r < 4; r++) {
                float mx = fmaxf(fmaxf(s[0][r], s[1][r]), fmaxf(s[2][r], s[3][r]));
#pragma unroll
                for (int off = 8; off; off >>= 1) mx = fmaxf(mx, __shfl_xor(mx, off, 16));
                float mo = ml_[mi][r];
                float mn = fmaxf(mo, mx);
                float alpha = __expf(mo - mn);
                ml_[mi][r] = mn;
                float p0 = __expf(s[0][r] - mn), p1 = __expf(s[1][r] - mn);
                float p2 = __expf(s[2][r] - mn), p3 = __expf(s[3][r] - mn);
                float ps = (p0 + p1) + (p2 + p3);
#pragma unroll
                for (int off = 8; off; off >>= 1) ps += __shfl_xor(ps, off, 16);
                ll_[mi][r] = ll_[mi][r] * alpha + ps;
#pragma unroll
                for (int ni = 0; ni < 4; ni++) acc[mi][ni][r] *= alpha;
                s[0][r] = p0; s[1][r] = p1; s[2][r] = p2; s[3][r] = p3;
            }
#pragma unroll
            for (int nt = 0; nt < 2; nt++)
#pragma unroll
                for (int r = 0; r < 4; r++)
                    pbuf[wave][(mi * 16 + quad * 4 + r) * PB_W + nt * 16 + l16] = f2b(s[nt][r]);
            s23[mi][0] = s[2]; s23[mi][1] = s[3];
        }

        __builtin_amdgcn_s_setprio(1);
#pragma unroll
        for (int mi = 0; mi < 2; mi++) {
            short8 pf = *(const short8*)(pbuf[wave] + (mi * 16 + l16) * PB_W + quad * 8);
#pragma unroll
            for (int ni = 0; ni < 4; ni++) {
                short8 vfn = *(const short8*)(Vt + (ni * 16 + l16) * AT_W + quad * 8);
                acc[mi][ni] = __builtin_amdgcn_mfma_f32_16x16x32_bf16(pf, vfn, acc[mi][ni], 0, 0, 0);
            }
        }
        __builtin_amdgcn_s_setprio(0);
#pragma unroll
        for (int mi = 0; mi < 2; mi++)
#pragma unroll
            for (int h = 0; h < 2; h++)
#pragma unroll
                for (int r = 0; r < 4; r++)
                    pbuf[wave][(mi * 16 + quad * 4 + r) * PB_W + h * 16 + l16] = f2b(s23[mi][h][r]);
        __builtin_amdgcn_s_setprio(1);
#pragma unroll
        for (int mi = 0; mi < 2; mi++) {
            short8 pf = *(const short8*)(pbuf[wave] + (mi * 16 + l16) * PB_W + quad * 8);
#pragma unroll
            for (int ni = 0; ni < 4; ni++) {
                short8 vfn = *(const short8*)(Vt + (ni * 16 + l16) * AT_W + 32 + quad * 8);
                acc[mi][ni] = __builtin_amdgcn_mfma_f32_16x16x32_bf16(pf, vfn, acc[mi][ni], 0, 0, 0);
            }
        }
        __builtin_amdgcn_s_setprio(0);
    }

#pragma unroll
    for (int mi = 0; mi < 2; mi++)
#pragma unroll
        for (int r = 0; r < 4; r++) {
            int tok = row0 + wave * 32 + mi * 16 + quad * 4 + r;
            if (tok < 196) {
                float inv = 1.f / ll_[mi][r];
                size_t ob = (size_t)(win * 196 + tok) * 768 + head * 64;
#pragma unroll
                for (int ni = 0; ni < 4; ni++)
                    out[ob + ni * 16 + l16] = f2b(acc[mi][ni][r] * inv);
            }
        }
}

// ---------------------------------------------------------------- launch
extern "C" void kernel_launch(void* const* d_in, const int* in_sizes, int n_in,
                              void* d_out, int out_size, void* d_ws, size_t ws_size,
                              hipStream_t stream)
{
    const float* x      = (const float*)d_in[0];
    const float* g1     = (const float*)d_in[1];
    const float* beta1  = (const float*)d_in[2];
    const float* w_qkv  = (const float*)d_in[3];
    const float* b_qkv  = (const float*)d_in[4];
    const float* w_proj = (const float*)d_in[5];
    const float* b_proj = (const float*)d_in[6];
    const float* rph    = (const float*)d_in[7];
    const float* rpw    = (const float*)d_in[8];
    const float* g2     = (const float*)d_in[9];
    const float* beta2  = (const float*)d_in[10];
    const float* w_fc1  = (const float*)d_in[11];
    const float* b_fc1  = (const float*)d_in[12];
    const float* w_fc2  = (const float*)d_in[13];
    const float* b_fc2  = (const float*)d_in[14];
    float* out = (float*)d_out;

    const size_t WT = 14155776;
    size_t b1 = 0, b2 = 0;
    int nc = 0, mc = 0;
    auto fits = [&](int a, int m) -> bool {
        size_t rows = (size_t)(200 / a) * 196, toks = (size_t)32768 / m;
        size_t bb1 = rows * 768 * 2 >= toks * 768 * 2 ? rows * 768 * 2 : toks * 768 * 2;
        size_t bb2 = rows * 2304 * 2 >= toks * 3072 * 2 ? rows * 2304 * 2 : toks * 3072 * 2;
        if (WT + bb1 + bb2 <= ws_size) { b1 = bb1; b2 = bb2; nc = a; mc = m; return true; }
        return false;
    };
    if (!fits(1, 1) && !fits(1, 2) && !fits(2, 2) && !fits(2, 4) && !fits(4, 4))
        return;   // diagnostic: leaves d_out untouched

    char* ws = (char*)d_ws;
    u16* wt0 = (u16*)ws;                               // qkv^T  2304x768
    u16* wt1 = wt0 + 2304 * 768;                       // proj^T  768x768
    u16* wt2 = wt1 + 768 * 768;                        // fc1^T  3072x768
    u16* wt3 = wt2 + 3072 * 768;                       // fc2^T   768x3072
    u16* buf1 = (u16*)(ws + WT);
    u16* buf2 = (u16*)(ws + WT + b1);

    dim3 blk(256), blk5(512);

    transpose_k<<<(768/32)*(2304/32), blk, 0, stream>>>(w_qkv,  wt0, 768, 2304);
    transpose_k<<<(768/32)*(768/32),  blk, 0, stream>>>(w_proj, wt1, 768, 768);
    transpose_k<<<(768/32)*(3072/32), blk, 0, stream>>>(w_fc1,  wt2, 768, 3072);
    transpose_k<<<(3072/32)*(768/32), blk, 0, stream>>>(w_fc2,  wt3, 3072, 768);

    // ---- attention phase: nc chunks of (200/nc) windows ----
    {
        const int nw = 200 / nc, rows = nw * 196;
        const int mt = (rows + 255) / 256;
        for (int c = 0; c < nc; c++) {
            const int rb = c * rows;
            ln_kernel<<<rows, blk, 0, stream>>>(x, g1, beta1, buf1, 1, rb);
            gemm256<0><<<dim3(mt * (2304/256)), blk5, 0, stream>>>(
                buf1, wt0, b_qkv, buf2, nullptr, rows, 2304, 768, 0);
            attn_mfma<<<nw * 24, blk, 0, stream>>>(buf2, rph, rpw, buf1);
            gemm256<1><<<dim3(mt * (768/256)), blk5, 0, stream>>>(
                buf1, wt1, b_proj, out, x, rows, 768, 768, rb);
        }
    }

    // ---- MLP phase: mc chunks of (32768/mc) tokens ----
    {
        const int tk = 32768 / mc;
        const int mt2 = (tk + 255) / 256;
        for (int c = 0; c < mc; c++) {
            const int rb = c * tk;
            ln_kernel<<<tk, blk, 0, stream>>>(
                out + (size_t)rb * 768, g2, beta2, buf1, 0, 0);
            gemm256<2><<<dim3(mt2 * (3072/256)), blk5, 0, stream>>>(
                buf1, wt2, b_fc1, buf2, nullptr, tk, 3072, 768, 0);
            gemm256<3><<<dim3(mt2 * (768/256)), blk5, 0, stream>>>(
                buf2, wt3, b_fc2, out, out, tk, 768, 3072, rb);
        }
    }
}

// Round 4
// 1545.306 us; speedup vs baseline: 1.0416x; 1.0416x over previous
//
#include <hip/hip_runtime.h>
#include <cstdint>

// Block_32401233281211: SAM-style windowed-attention transformer block.
// I/O dtype: FLOAT32. Internal GEMMs + attention: bf16 MFMA.
// B=8, H=W=64, C=768, heads=12, hd=64, FF=3072, WS=14 -> pad to 70x70,
// 200 windows x 196 tokens = 39200 window-token rows.
// R8: attention half-blocks (~200us, kept). R9: 256x256 pipelined GEMM FAILED:
//     runtime-indexed LDS dbuf -> AA fail -> legalizer vmcnt(0) drain before
//     every compute (MfmaUtil 17.7%); 384-block fc2 grid; 1 block/CU.
// R10 (this round): gemm128 pipelined:
//   - 128x128 BK=64, 4 waves, LDS 64 KB -> 2 blocks/CU (TLP restored)
//   - FOUR DISTINCT static __shared__ arrays + unrolled even/odd bodies:
//     compile-time disjointness lets AA drop the forced drain; vmcnt(8)
//     keeps next tile's 8 loads in flight across the barrier (T3/T4)
//   - R9's verified XOR swizzle kept (0 bank conflicts)
//   - all grids >= 1536 blocks

typedef unsigned short u16;
typedef __attribute__((ext_vector_type(8))) short short8;   // 8 x bf16
typedef __attribute__((ext_vector_type(4))) float f32x4;

__device__ __forceinline__ u16 f2b(float f) {
    union { float f; unsigned int i; } x; x.f = f;
    unsigned int u = x.i;
    return (u16)((u + 0x7fffu + ((u >> 16) & 1u)) >> 16);   // RNE
}
__device__ __forceinline__ float b2f(u16 u) {
    union { unsigned int i; float f; } x; x.i = ((unsigned int)u) << 16; return x.f;
}

// async global->LDS, 16 B per lane. LDS dest = wave-uniform base + lane*16.
__device__ __forceinline__ void gload16(const u16* g, u16* l) {
    __builtin_amdgcn_global_load_lds(
        (const __attribute__((address_space(1))) unsigned int*)g,
        (__attribute__((address_space(3))) unsigned int*)l, 16, 0, 0);
}

// bijective XCD swizzle (m204)
__device__ __forceinline__ int xcd_swz(int bid, int nwg) {
    int q = nwg >> 3, r = nwg & 7;
    int x = bid & 7, lo = bid >> 3;
    return (x < r ? x * (q + 1) : r * (q + 1) + (x - r) * q) + lo;
}

// ---------------------------------------------------------------- transpose
__global__ __launch_bounds__(256) void transpose_k(
    const float* __restrict__ in, u16* __restrict__ out, int R, int C)
{
    __shared__ float tile[32][33];
    int bpc = C >> 5;
    int r0 = (blockIdx.x / bpc) << 5;
    int c0 = (blockIdx.x % bpc) << 5;
    int lx = threadIdx.x & 31, ly = threadIdx.x >> 5;
#pragma unroll
    for (int s = 0; s < 32; s += 8)
        tile[ly + s][lx] = in[(size_t)(r0 + ly + s) * C + c0 + lx];
    __syncthreads();
#pragma unroll
    for (int s = 0; s < 32; s += 8)
        out[(size_t)(c0 + ly + s) * R + r0 + lx] = f2b(tile[lx][ly + s]);
}

// ---------------------------------------------------------------- layernorm
__global__ __launch_bounds__(256) void ln_kernel(
    const float* __restrict__ in, const float* __restrict__ g,
    const float* __restrict__ beta, u16* __restrict__ out, int windowed,
    int row_base)
{
    __shared__ float sbuf[4];
    int tid = threadIdx.x;
    size_t orow = (size_t)blockIdx.x * 768;
    size_t irow;
    if (windowed) {
        int r = row_base + blockIdx.x;
        int win = r / 196, t = r % 196;
        int p = t / 14, q = t % 14;
        int b = win / 25, wt = win % 25;
        int i = (wt / 5) * 14 + p, j = (wt % 5) * 14 + q;
        if (i >= 64 || j >= 64) {
            out[orow + tid] = 0; out[orow + tid + 256] = 0; out[orow + tid + 512] = 0;
            return;
        }
        irow = (((size_t)b * 64 + i) * 64 + j) * 768;
    } else {
        irow = (size_t)blockIdx.x * 768;
    }
    float v0 = in[irow + tid];
    float v1 = in[irow + tid + 256];
    float v2 = in[irow + tid + 512];
    float s = v0 + v1 + v2;
#pragma unroll
    for (int off = 32; off; off >>= 1) s += __shfl_xor(s, off, 64);
    if ((tid & 63) == 0) sbuf[tid >> 6] = s;
    __syncthreads();
    float mean = (sbuf[0] + sbuf[1] + sbuf[2] + sbuf[3]) * (1.f / 768.f);
    __syncthreads();
    float d0 = v0 - mean, d1 = v1 - mean, d2 = v2 - mean;
    float sq = d0 * d0 + d1 * d1 + d2 * d2;
#pragma unroll
    for (int off = 32; off; off >>= 1) sq += __shfl_xor(sq, off, 64);
    if ((tid & 63) == 0) sbuf[tid >> 6] = sq;
    __syncthreads();
    float var = (sbuf[0] + sbuf[1] + sbuf[2] + sbuf[3]) * (1.f / 768.f);
    float rs = rsqrtf(var + 1e-6f);
    out[orow + tid]       = f2b(d0 * rs * g[tid]       + beta[tid]);
    out[orow + tid + 256] = f2b(d1 * rs * g[tid + 256] + beta[tid + 256]);
    out[orow + tid + 512] = f2b(d2 * rs * g[tid + 512] + beta[tid + 512]);
}

// ---------------------------------------------------------------- GEMM 128x128
// C(MxN) = A(MxK) @ Bt(NxK)^T + bias, bf16 in / f32 acc, MFMA 16x16x32.
// 256 threads = 4 waves (2M x 2N); wave tile 64x64 = acc[4][4].
// LDS: 4 distinct static arrays (As0/As1/Bs0/Bs1, 16 KB each) -> AA-provable
// disjointness -> no compiler-forced vmcnt(0) before ds_reads.
// Per tile: stage = 8 gload16/thread (4 A + 4 B); each instr = 8 rows x 128 B,
// lane i -> row (i>>3), src k-chunk (i&7)^(i>>3) (inverse swizzle), LDS linear.
// Read: frag(row,ks) at row*64 + (((ks*4+quad)^(row&7))*8; row&7 == lane&7.
// Pipeline per iteration (2 K-tiles, nth = K/128 iters, K%128==0):
//   B | stage(2it+1 -> S1) | vmcnt(8) | B | compute S0
//   B | stage(2it+2 -> S0)?| vmcnt(8/0) | B | compute S1
// vmcnt(8) = just-issued 8 stay in flight, previous tile's 8 retired (T4).
// Tail M-rows stage garbage (land in adjacent workspace); epilogue skips.

__device__ __forceinline__ void compute_tile(
    const u16* Ab, const u16* Bb, f32x4 (&acc)[4][4],
    int wr, int wc, int quad, int l16, int l7)
{
    short8 a_[4][2], b_[4][2];
#pragma unroll
    for (int m = 0; m < 4; m++)
#pragma unroll
        for (int ks = 0; ks < 2; ks++)
            a_[m][ks] = *(const short8*)(Ab + (wr * 64 + m * 16 + l16) * 64
                                            + ((((ks << 2) + quad) ^ l7) << 3));
#pragma unroll
    for (int n = 0; n < 4; n++)
#pragma unroll
        for (int ks = 0; ks < 2; ks++)
            b_[n][ks] = *(const short8*)(Bb + (wc * 64 + n * 16 + l16) * 64
                                            + ((((ks << 2) + quad) ^ l7) << 3));
    __builtin_amdgcn_s_setprio(1);
#pragma unroll
    for (int m = 0; m < 4; m++)
#pragma unroll
        for (int n = 0; n < 4; n++)
#pragma unroll
            for (int ks = 0; ks < 2; ks++)
                acc[m][n] = __builtin_amdgcn_mfma_f32_16x16x32_bf16(
                    a_[m][ks], b_[n][ks], acc[m][n], 0, 0, 0);
    __builtin_amdgcn_s_setprio(0);
}

template <int EPI>
__global__ __launch_bounds__(256) void gemm128(
    const u16* __restrict__ A, const u16* __restrict__ Bt,
    const float* __restrict__ bias, void* __restrict__ CoutV,
    const float* __restrict__ resid, int M, int N, int K, int row_base)
{
    __shared__ __align__(16) u16 As0[128 * 64];
    __shared__ __align__(16) u16 As1[128 * 64];
    __shared__ __align__(16) u16 Bs0[128 * 64];
    __shared__ __align__(16) u16 Bs1[128 * 64];

    const int tid = threadIdx.x;
    const int lane = tid & 63, wave = tid >> 6;
    const int wr = wave >> 1, wc = wave & 1;
    const int quad = lane >> 4, l16 = lane & 15, l7 = lane & 7;
    const int ntile = N / 128;
    const int swz = xcd_swz(blockIdx.x, gridDim.x);
    const int m0 = (swz / ntile) * 128;
    const int n0 = (swz % ntile) * 128;

    // staging lane constants (verified R9 swizzle, 0 bank conflicts)
    const int rl = lane >> 3;
    const int cl = ((lane & 7) ^ rl) << 3;
    int aoff[4], boff[4];
#pragma unroll
    for (int q = 0; q < 4; q++) {
        aoff[q] = (m0 + wave * 32 + q * 8 + rl) * K + cl;
        boff[q] = (n0 + wave * 32 + q * 8 + rl) * K + cl;
    }
    const int lws = wave * 32 * 64;   // wave's staging base (elems)

    f32x4 acc[4][4] = {};
    const int nth = K >> 7;           // K/128, 2 K-tiles per iteration

    // prologue: tile 0 -> S0
#pragma unroll
    for (int q = 0; q < 4; q++) {
        gload16(A  + aoff[q], As0 + lws + q * 512);
        gload16(Bt + boff[q], Bs0 + lws + q * 512);
    }

#pragma unroll 1
    for (int it = 0; it < nth; ++it) {
        // ---- phase A: stage tile 2it+1 -> S1, compute tile 2it from S0
        __builtin_amdgcn_sched_barrier(0);
        __builtin_amdgcn_s_barrier();            // S1 reads (prev iter) done chip-wide
        __builtin_amdgcn_sched_barrier(0);
        {
            const int k1 = (2 * it + 1) << 6;
#pragma unroll
            for (int q = 0; q < 4; q++) {
                gload16(A  + aoff[q] + k1, As1 + lws + q * 512);
                gload16(Bt + boff[q] + k1, Bs1 + lws + q * 512);
            }
        }
        __builtin_amdgcn_sched_barrier(0);
        asm volatile("s_waitcnt vmcnt(8)" ::: "memory");   // tile 2it resident (this wave)
        __builtin_amdgcn_sched_barrier(0);
        __builtin_amdgcn_s_barrier();            // ... and for all waves
        __builtin_amdgcn_sched_barrier(0);
        compute_tile(As0, Bs0, acc, wr, wc, quad, l16, l7);

        // ---- phase B: stage tile 2it+2 -> S0 (if any), compute tile 2it+1 from S1
        __builtin_amdgcn_sched_barrier(0);
        __builtin_amdgcn_s_barrier();            // S0 reads done chip-wide
        __builtin_amdgcn_sched_barrier(0);
        if (it + 1 < nth) {
            const int k2 = (2 * it + 2) << 6;
#pragma unroll
            for (int q = 0; q < 4; q++) {
                gload16(A  + aoff[q] + k2, As0 + lws + q * 512);
                gload16(Bt + boff[q] + k2, Bs0 + lws + q * 512);
            }
            __builtin_amdgcn_sched_barrier(0);
            asm volatile("s_waitcnt vmcnt(8)" ::: "memory");
        } else {
            __builtin_amdgcn_sched_barrier(0);
            asm volatile("s_waitcnt vmcnt(0)" ::: "memory");
        }
        __builtin_amdgcn_sched_barrier(0);
        __builtin_amdgcn_s_barrier();
        __builtin_amdgcn_sched_barrier(0);
        compute_tile(As1, Bs1, acc, wr, wc, quad, l16, l7);
    }

    // ---- epilogue (identical to R8's gemm_bt)
#pragma unroll
    for (int mi = 0; mi < 4; mi++) {
#pragma unroll
        for (int ni = 0; ni < 4; ni++) {
            const int gn = n0 + wc * 64 + ni * 16 + l16;
            const float bv = bias[gn];
#pragma unroll
            for (int r = 0; r < 4; r++) {
                const int row = m0 + wr * 64 + mi * 16 + quad * 4 + r;
                if (row >= M) continue;
                float v = acc[mi][ni][r] + bv;
                if (EPI == 0) {
                    ((u16*)CoutV)[(size_t)row * N + gn] = f2b(v);
                } else if (EPI == 1) {
                    int grow = row_base + row;
                    int win = grow / 196, t = grow % 196;
                    int p = t / 14, q = t % 14;
                    int b_ = win / 25, wt = win % 25;
                    int i = (wt / 5) * 14 + p, j = (wt % 5) * 14 + q;
                    if (i < 64 && j < 64) {
                        size_t idx = (((size_t)b_ * 64 + i) * 64 + j) * 768 + gn;
                        ((float*)CoutV)[idx] = resid[idx] + v;
                    }
                } else if (EPI == 2) {
                    float gl = 0.5f * v * (1.0f + erff(v * 0.70710678118654752f));
                    ((u16*)CoutV)[(size_t)row * N + gn] = f2b(gl);
                } else {
                    size_t idx = (size_t)(row_base + row) * 768 + gn;
                    ((float*)CoutV)[idx] = resid[idx] + v;
                }
            }
        }
    }
}

// ---------------------------------------------------------------- attention v5
// (unchanged from R8 — verified passing)
#define AT_W 72
#define PB_W 40

__global__ __launch_bounds__(256) void attn_mfma(
    const u16* __restrict__ qkv,          // [nw*196][2304] = [..][3][12][64]
    const float* __restrict__ relh, const float* __restrict__ relw, // [27][64]
    u16* __restrict__ out)                // [nw*196][768]
{
    __shared__ __align__(16) u16 pbuf[4][32 * PB_W];     // 10240 B (rel_ext alias)
    __shared__ __align__(16) u16 Kc[64 * AT_W];          //  9216 B
    __shared__ __align__(16) u16 Vt[64 * AT_W];          //  9216 B
    u16* rel_ext = &pbuf[0][0];                          // 128*32*2 = 8192 B

    const int nwg = gridDim.x;
    const int swzb = xcd_swz(blockIdx.x, nwg);
    const int win = swzb / 24, rem = swzb % 24;
    const int head = rem >> 1, half = rem & 1;
    const int row0 = half * 128;
    const int tid = threadIdx.x, lane = tid & 63, wave = tid >> 6;
    const int quad = lane >> 4, l16 = lane & 15;
    const size_t base = (size_t)win * 196 * 2304 + (size_t)head * 64;

    short8 qf[2][2];
#pragma unroll
    for (int mi = 0; mi < 2; mi++) {
        int tok = row0 + wave * 32 + mi * 16 + l16;
        int rt = tok < 196 ? tok : 195;
        const u16* qp = qkv + base + (size_t)rt * 2304 + quad * 8;
        qf[mi][0] = *(const short8*)(qp);
        qf[mi][1] = *(const short8*)(qp + 32);
    }

    for (int e = tid; e < 64 * 64; e += 256) {
        int rr = e >> 6, cc = e & 63;
        float v = 0.f;
        if (rr < 27)      v = 8.f * relh[rr * 64 + cc];
        else if (rr < 54) v = 8.f * relw[(rr - 27) * 64 + cc];
        Kc[rr * AT_W + cc] = f2b(v);
    }
    if (tid < 128) {
        u16* rp = rel_ext + tid * 32;
        uint4 z = make_uint4(0u, 0u, 0u, 0u);
        *(uint4*)(rp) = z; *(uint4*)(rp + 8) = z;
        *(uint4*)(rp + 16) = z; *(uint4*)(rp + 24) = z;
        rp[31] = f2b(-1e30f);
    }
    __syncthreads();

#pragma unroll
    for (int cb = 0; cb < 2; cb++) {
#pragma unroll
        for (int nt = 0; nt < 2; nt++) {
            const u16* kp_ = Kc + (cb * 32 + nt * 16 + l16) * AT_W + quad * 8;
            short8 b0 = *(const short8*)(kp_);
            short8 b1 = *(const short8*)(kp_ + 32);
            int i = cb * 32 + nt * 16 + l16;
#pragma unroll
            for (int mi = 0; mi < 2; mi++) {
                f32x4 c = {};
                c = __builtin_amdgcn_mfma_f32_16x16x32_bf16(qf[mi][0], b0, c, 0, 0, 0);
                c = __builtin_amdgcn_mfma_f32_16x16x32_bf16(qf[mi][1], b1, c, 0, 0, 0);
#pragma unroll
                for (int r = 0; r < 4; r++) {
                    int row = wave * 32 + mi * 16 + quad * 4 + r;
                    int grow = row0 + row;
                    int rowB = grow < 196 ? grow : 195;
                    int p = rowB / 14, qq = rowB % 14;
                    if (i < 27) {
                        int t = p + 13 - i;
                        if (t >= 0 && t < 14) rel_ext[row * 32 + t] = f2b(c[r]);
                    } else if (i < 54) {
                        int t = qq + 13 - (i - 27);
                        if (t >= 0 && t < 14) rel_ext[row * 32 + 14 + t] = f2b(c[r]);
                    }
                }
            }
        }
    }
    short8 qe[2];
#pragma unroll
    for (int mi = 0; mi < 2; mi++)
        qe[mi] = *(const short8*)(rel_ext + (wave * 32 + mi * 16 + l16) * 32 + quad * 8);

    f32x4 acc[2][4] = {};
    float ml_[2][4], ll_[2][4];
#pragma unroll
    for (int mi = 0; mi < 2; mi++)
#pragma unroll
        for (int r = 0; r < 4; r++) { ml_[mi][r] = -1e30f; ll_[mi][r] = 0.f; }

#pragma unroll 1
    for (int c = 0; c < 4; c++) {
        const int kbase = c * 64;
        __syncthreads();
        {
            int key = tid >> 2;
            int cg  = (tid & 3) << 4;
            int gk = kbase + key;
            uint4 k0 = make_uint4(0u,0u,0u,0u), k1 = k0, v0 = k0, v1 = k0;
            if (gk < 196) {
                const u16* kp_ = qkv + base + 768  + (size_t)gk * 2304 + cg;
                const u16* vp_ = qkv + base + 1536 + (size_t)gk * 2304 + cg;
                k0 = *(const uint4*)(kp_); k1 = *(const uint4*)(kp_ + 8);
                v0 = *(const uint4*)(vp_); v1 = *(const uint4*)(vp_ + 8);
            }
            *(uint4*)(Kc + key * AT_W + cg)     = k0;
            *(uint4*)(Kc + key * AT_W + cg + 8) = k1;
            union { uint4 u; u16 h[8]; } a, b; a.u = v0; b.u = v1;
#pragma unroll
            for (int i = 0; i < 8; i++) Vt[(cg + i) * AT_W + key] = a.h[i];
#pragma unroll
            for (int i = 0; i < 8; i++) Vt[(cg + 8 + i) * AT_W + key] = b.h[i];
        }
        __syncthreads();

        short8 bo[4];
        {
            const u16 one = 0x3F80;
#pragma unroll
            for (int nt = 0; nt < 4; nt++) {
                int key = kbase + nt * 16 + l16;
                int inval = key >= 196;
                int kp = key / 14, kq = key - kp * 14;
                union { short8 s; u16 h[8]; } u;
#pragma unroll
                for (int j = 0; j < 8; j++) {
                    int t = quad * 8 + j;
                    u16 v = 0;
                    if (!inval && t == kp) v = one;
                    if (!inval && t >= 14 && (t - 14) == kq) v = one;
                    if (inval && t == 31) v = one;
                    u.h[j] = v;
                }
                bo[nt] = u.s;
            }
        }

        f32x4 s23[2][2];
#pragma unroll
        for (int mi = 0; mi < 2; mi++) {
            f32x4 s[4];
            __builtin_amdgcn_s_setprio(1);
#pragma unroll
            for (int nt = 0; nt < 4; nt++) {
                const u16* kp_ = Kc + (nt * 16 + l16) * AT_W + quad * 8;
                short8 kf0 = *(const short8*)(kp_);
                short8 kf1 = *(const short8*)(kp_ + 32);
                f32x4 t = {};
                t = __builtin_amdgcn_mfma_f32_16x16x32_bf16(qf[mi][0], kf0, t, 0, 0, 0);
                t = __builtin_amdgcn_mfma_f32_16x16x32_bf16(qf[mi][1], kf1, t, 0, 0, 0);
                t = __builtin_amdgcn_mfma_f32_16x16x32_bf16(qe[mi],    bo[nt], t, 0, 0, 0);
                s[nt] = t * 0.125f;
            }
            __builtin_amdgcn_s_setprio(0);
#pragma unroll
            for (int r = 0; r < 4; r++) {
                float mx = fmaxf(fmaxf(s[0][r], s[1][r]), fmaxf(s[2][r], s[3][r]));
#pragma unroll
                for (int off = 8; off; off >>= 1) mx = fmaxf(mx, __shfl_xor(mx, off, 16));
                float mo = ml_[mi][r];
                float mn = fmaxf(mo, mx);
                float alpha = __expf(mo - mn);
                ml_[mi][r] = mn;
                float p0 = __expf(s[0][r] - mn), p1 = __expf(s[1][r] - mn);
                float p2 = __expf(s[2][r] - mn), p3 = __expf(s[3][r] - mn);
                float ps = (p0 + p1) + (p2 + p3);
#pragma unroll
                for (int off = 8; off; off >>= 1) ps += __shfl_xor(ps, off, 16);
                ll_[mi][r] = ll_[mi][r] * alpha + ps;
#pragma unroll
                for (int ni = 0; ni < 4; ni++) acc[mi][ni][r] *= alpha;
                s[0][r] = p0; s[1][r] = p1; s[2][r] = p2; s[3][r] = p3;
            }
#pragma unroll
            for (int nt = 0; nt < 2; nt++)
#pragma unroll
                for (int r = 0; r < 4; r++)
                    pbuf[wave][(mi * 16 + quad * 4 + r) * PB_W + nt * 16 + l16] = f2b(s[nt][r]);
            s23[mi][0] = s[2]; s23[mi][1] = s[3];
        }

        __builtin_amdgcn_s_setprio(1);
#pragma unroll
        for (int mi = 0; mi < 2; mi++) {
            short8 pf = *(const short8*)(pbuf[wave] + (mi * 16 + l16) * PB_W + quad * 8);
#pragma unroll
            for (int ni = 0; ni < 4; ni++) {
                short8 vfn = *(const short8*)(Vt + (ni * 16 + l16) * AT_W + quad * 8);
                acc[mi][ni] = __builtin_amdgcn_mfma_f32_16x16x32_bf16(pf, vfn, acc[mi][ni], 0, 0, 0);
            }
        }
        __builtin_amdgcn_s_setprio(0);
#pragma unroll
        for (int mi = 0; mi < 2; mi++)
#pragma unroll
            for (int h = 0; h < 2; h++)
#pragma unroll
                for (int r = 0; r < 4; r++)
                    pbuf[wave][(mi * 16 + quad * 4 + r) * PB_W + h * 16 + l16] = f2b(s23[mi][h][r]);
        __builtin_amdgcn_s_setprio(1);
#pragma unroll
        for (int mi = 0; mi < 2; mi++) {
            short8 pf = *(const short8*)(pbuf[wave] + (mi * 16 + l16) * PB_W + quad * 8);
#pragma unroll
            for (int ni = 0; ni < 4; ni++) {
                short8 vfn = *(const short8*)(Vt + (ni * 16 + l16) * AT_W + 32 + quad * 8);
                acc[mi][ni] = __builtin_amdgcn_mfma_f32_16x16x32_bf16(pf, vfn, acc[mi][ni], 0, 0, 0);
            }
        }
        __builtin_amdgcn_s_setprio(0);
    }

#pragma unroll
    for (int mi = 0; mi < 2; mi++)
#pragma unroll
        for (int r = 0; r < 4; r++) {
            int tok = row0 + wave * 32 + mi * 16 + quad * 4 + r;
            if (tok < 196) {
                float inv = 1.f / ll_[mi][r];
                size_t ob = (size_t)(win * 196 + tok) * 768 + head * 64;
#pragma unroll
                for (int ni = 0; ni < 4; ni++)
                    out[ob + ni * 16 + l16] = f2b(acc[mi][ni][r] * inv);
            }
        }
}

// ---------------------------------------------------------------- launch
extern "C" void kernel_launch(void* const* d_in, const int* in_sizes, int n_in,
                              void* d_out, int out_size, void* d_ws, size_t ws_size,
                              hipStream_t stream)
{
    const float* x      = (const float*)d_in[0];
    const float* g1     = (const float*)d_in[1];
    const float* beta1  = (const float*)d_in[2];
    const float* w_qkv  = (const float*)d_in[3];
    const float* b_qkv  = (const float*)d_in[4];
    const float* w_proj = (const float*)d_in[5];
    const float* b_proj = (const float*)d_in[6];
    const float* rph    = (const float*)d_in[7];
    const float* rpw    = (const float*)d_in[8];
    const float* g2     = (const float*)d_in[9];
    const float* beta2  = (const float*)d_in[10];
    const float* w_fc1  = (const float*)d_in[11];
    const float* b_fc1  = (const float*)d_in[12];
    const float* w_fc2  = (const float*)d_in[13];
    const float* b_fc2  = (const float*)d_in[14];
    float* out = (float*)d_out;

    const size_t WT = 14155776;
    size_t b1 = 0, b2 = 0;
    int nc = 0, mc = 0;
    auto fits = [&](int a, int m) -> bool {
        size_t rows = (size_t)(200 / a) * 196, toks = (size_t)32768 / m;
        size_t bb1 = rows * 768 * 2 >= toks * 768 * 2 ? rows * 768 * 2 : toks * 768 * 2;
        size_t bb2 = rows * 2304 * 2 >= toks * 3072 * 2 ? rows * 2304 * 2 : toks * 3072 * 2;
        if (WT + bb1 + bb2 <= ws_size) { b1 = bb1; b2 = bb2; nc = a; mc = m; return true; }
        return false;
    };
    if (!fits(1, 1) && !fits(1, 2) && !fits(2, 2) && !fits(2, 4) && !fits(4, 4))
        return;   // diagnostic: leaves d_out untouched

    char* ws = (char*)d_ws;
    u16* wt0 = (u16*)ws;                               // qkv^T  2304x768
    u16* wt1 = wt0 + 2304 * 768;                       // proj^T  768x768
    u16* wt2 = wt1 + 768 * 768;                        // fc1^T  3072x768
    u16* wt3 = wt2 + 3072 * 768;                       // fc2^T   768x3072
    u16* buf1 = (u16*)(ws + WT);
    u16* buf2 = (u16*)(ws + WT + b1);

    dim3 blk(256);

    transpose_k<<<(768/32)*(2304/32), blk, 0, stream>>>(w_qkv,  wt0, 768, 2304);
    transpose_k<<<(768/32)*(768/32),  blk, 0, stream>>>(w_proj, wt1, 768, 768);
    transpose_k<<<(768/32)*(3072/32), blk, 0, stream>>>(w_fc1,  wt2, 768, 3072);
    transpose_k<<<(3072/32)*(768/32), blk, 0, stream>>>(w_fc2,  wt3, 3072, 768);

    // ---- attention phase: nc chunks of (200/nc) windows ----
    {
        const int nw = 200 / nc, rows = nw * 196;
        const int mt = (rows + 127) / 128;
        for (int c = 0; c < nc; c++) {
            const int rb = c * rows;
            ln_kernel<<<rows, blk, 0, stream>>>(x, g1, beta1, buf1, 1, rb);
            gemm128<0><<<dim3(mt * (2304/128)), blk, 0, stream>>>(
                buf1, wt0, b_qkv, buf2, nullptr, rows, 2304, 768, 0);
            attn_mfma<<<nw * 24, blk, 0, stream>>>(buf2, rph, rpw, buf1);
            gemm128<1><<<dim3(mt * (768/128)), blk, 0, stream>>>(
                buf1, wt1, b_proj, out, x, rows, 768, 768, rb);
        }
    }

    // ---- MLP phase: mc chunks of (32768/mc) tokens ----
    {
        const int tk = 32768 / mc;
        const int mt2 = tk / 128;
        for (int c = 0; c < mc; c++) {
            const int rb = c * tk;
            ln_kernel<<<tk, blk, 0, stream>>>(
                out + (size_t)rb * 768, g2, beta2, buf1, 0, 0);
            gemm128<2><<<dim3(mt2 * (3072/128)), blk, 0, stream>>>(
                buf1, wt2, b_fc1, buf2, nullptr, tk, 3072, 768, 0);
            gemm128<3><<<dim3(mt2 * (768/128)), blk, 0, stream>>>(
                buf2, wt3, b_fc2, out, out, tk, 768, 3072, rb);
        }
    }
}